// Round 15
// baseline (332.086 us; speedup 1.0000x reference)
//
#include <hip/hip_runtime.h>
#include <stdint.h>

using f32x4  = __attribute__((ext_vector_type(4))) float;
using f32x16 = __attribute__((ext_vector_type(16))) float;
using f16x8  = __attribute__((ext_vector_type(8))) _Float16;

#define NB  16
#define NC  256
#define NC2 128
#define NN  4096
#define TILE_B 49152   // 48 KB/tile: K 16K (16 planes x 64key x 16B) + V 32K (8 planes x 256o x 16B)
#define LOG2E 1.44269504f

__device__ __forceinline__ unsigned int pk2(float a, float b) {
    auto h = __builtin_amdgcn_cvt_pkrtz(a, b);   // __fp16 ext_vector(2)
    return __builtin_bit_cast(unsigned int, h);
}

__device__ __forceinline__ f16x8 pack8(f32x4 a, f32x4 b) {
    union { unsigned int w[4]; f16x8 v; } u;
    u.w[0] = pk2(a[0], a[1]); u.w[1] = pk2(a[2], a[3]);
    u.w[2] = pk2(b[0], b[1]); u.w[3] = pk2(b[2], b[3]);
    return u.v;
}

__device__ __forceinline__ void gload16(const void* g, void* l) {
    __builtin_amdgcn_global_load_lds(
        (const __attribute__((address_space(1))) unsigned int*)g,
        (__attribute__((address_space(3))) unsigned int*)l, 16, 0, 0);
}

// ---------------------------------------------------------------------------
// Phase 1: 1x1-conv projections as MFMA f16 GEMM, LDS-staged epilogue.
// (round-13-proven single-pass structure; ONLY change: K image is now
// fragment-major planes [p=c>>3][key][16B] so attn can read K fragments as
// perfectly-coalesced GLOBAL loads — no K LDS staging in attn.)
// Q pre-scaled by log2(e); V image granule-transposed [g][o][16B].
// ---------------------------------------------------------------------------
__global__ __launch_bounds__(256, 2) void qkv_kernel(
    const float* __restrict__ x, const float* __restrict__ y,
    const float* __restrict__ Wq, const float* __restrict__ bq,
    const float* __restrict__ Wk, const float* __restrict__ bk,
    const float* __restrict__ Wv, const float* __restrict__ bv,
    unsigned short* __restrict__ Qf, char* __restrict__ KV)
{
    __shared__ __align__(16) char lds[65536];

    const int bid   = blockIdx.x;
    const int ntile = bid & 63;
    const int bb    = bid >> 6;
    const int nblk  = ntile * 64;

    const int t    = threadIdx.x;
    const int lane = t & 63;
    const int wid  = t >> 6;
    const int l31  = lane & 31;
    const int s    = lane >> 5;

    // ---------------- pass 1: Q (waves 0-1) / K (waves 2-3) ----------------
    {
        const bool isQ = (wid < 2);
        const float* srcb = (isQ ? x : y) + (size_t)bb * NC * NN;
        const float* W    = isQ ? Wq : Wk;
        const float* bias = isQ ? bq : bk;
        const int wo = (wid & 1) * 64;
        const float osc = isQ ? LOG2E : 1.0f;

        f32x16 acc[2][2];
        #pragma unroll
        for (int a = 0; a < 2; ++a)
            #pragma unroll
            for (int bc = 0; bc < 2; ++bc) acc[a][bc] = (f32x16)(0.0f);

        #pragma unroll 4
        for (int ks = 0; ks < 16; ++ks) {
            const int c0 = ks * 16 + s * 8;
            f16x8 wf[2], xf[2];
            #pragma unroll
            for (int a = 0; a < 2; ++a) {
                const float* wr = W + (size_t)(wo + a * 32 + l31) * NC + c0;
                wf[a] = pack8(*(const f32x4*)wr, *(const f32x4*)(wr + 4));
            }
            #pragma unroll
            for (int bc = 0; bc < 2; ++bc) {
                const float* xc = srcb + (size_t)c0 * NN + nblk + bc * 32 + l31;
                f32x4 v0, v1;
                v0[0] = xc[0*NN]; v0[1] = xc[1*NN]; v0[2] = xc[2*NN]; v0[3] = xc[3*NN];
                v1[0] = xc[4*NN]; v1[1] = xc[5*NN]; v1[2] = xc[6*NN]; v1[3] = xc[7*NN];
                xf[bc] = pack8(v0, v1);
            }
            #pragma unroll
            for (int a = 0; a < 2; ++a)
                #pragma unroll
                for (int bc = 0; bc < 2; ++bc)
                    acc[a][bc] = __builtin_amdgcn_mfma_f32_32x32x16_f16(
                        wf[a], xf[bc], acc[a][bc], 0, 0, 0);
        }

        #pragma unroll
        for (int a = 0; a < 2; ++a) {
            #pragma unroll
            for (int bc = 0; bc < 2; ++bc) {
                const int nr = bc * 32 + l31;
                #pragma unroll
                for (int g = 0; g < 4; ++g) {
                    const int o0 = wo + a * 32 + 8 * g + 4 * s;
                    const f32x4 bv4 = *(const f32x4*)(bias + o0);
                    union { unsigned int w[2]; uint2 u2; } pk;
                    pk.w[0] = pk2((acc[a][bc][g*4+0] + bv4[0]) * osc,
                                  (acc[a][bc][g*4+1] + bv4[1]) * osc);
                    pk.w[1] = pk2((acc[a][bc][g*4+2] + bv4[2]) * osc,
                                  (acc[a][bc][g*4+3] + bv4[3]) * osc);
                    int dst;
                    if (isQ) {
                        dst = 49152 + nr*256 +
                            (((o0 >> 3) << 4) ^ ((nr & 15) << 4)) + (o0 & 7) * 2;
                    } else {
                        // K fragment-major: plane p = o0>>3, row = key, 16B/row
                        dst = ((o0 >> 3) << 10) + nr*16 + (o0 & 7) * 2;
                    }
                    *(uint2*)(lds + dst) = pk.u2;
                }
            }
        }
    }

    // ---------------- pass 2: V (all waves, swapped mfma) ----------------
    {
        const float* srcb = y + (size_t)bb * NC * NN;
        const int wo = wid * 64;

        f32x16 acc[2][2];
        #pragma unroll
        for (int a = 0; a < 2; ++a)
            #pragma unroll
            for (int bc = 0; bc < 2; ++bc) acc[a][bc] = (f32x16)(0.0f);

        #pragma unroll 4
        for (int ks = 0; ks < 16; ++ks) {
            const int c0 = ks * 16 + s * 8;
            f16x8 wf[2], xf[2];
            #pragma unroll
            for (int a = 0; a < 2; ++a) {
                const float* wr = Wv + (size_t)(wo + a * 32 + l31) * NC + c0;
                wf[a] = pack8(*(const f32x4*)wr, *(const f32x4*)(wr + 4));
            }
            #pragma unroll
            for (int bc = 0; bc < 2; ++bc) {
                const float* xc = srcb + (size_t)c0 * NN + nblk + bc * 32 + l31;
                f32x4 v0, v1;
                v0[0] = xc[0*NN]; v0[1] = xc[1*NN]; v0[2] = xc[2*NN]; v0[3] = xc[3*NN];
                v1[0] = xc[4*NN]; v1[1] = xc[5*NN]; v1[2] = xc[6*NN]; v1[3] = xc[7*NN];
                xf[bc] = pack8(v0, v1);
            }
            #pragma unroll
            for (int a = 0; a < 2; ++a)
                #pragma unroll
                for (int bc = 0; bc < 2; ++bc)
                    acc[a][bc] = __builtin_amdgcn_mfma_f32_32x32x16_f16(
                        xf[bc], wf[a], acc[a][bc], 0, 0, 0);
        }

        #pragma unroll
        for (int a = 0; a < 2; ++a) {
            const int o = wo + a * 32 + l31;
            const float bvo = bv[o];
            #pragma unroll
            for (int bc = 0; bc < 2; ++bc) {
                #pragma unroll
                for (int g = 0; g < 4; ++g) {
                    const int nr = bc * 32 + 8 * g + 4 * s;   // keys nr..nr+3
                    union { unsigned int w[2]; uint2 u2; } pk;
                    pk.w[0] = pk2(acc[a][bc][g*4+0] + bvo, acc[a][bc][g*4+1] + bvo);
                    pk.w[1] = pk2(acc[a][bc][g*4+2] + bvo, acc[a][bc][g*4+3] + bvo);
                    const int dst = 16384 + ((nr >> 3) << 12) + o*16 + (nr & 7) * 2;
                    *(uint2*)(lds + dst) = pk.u2;
                }
            }
        }
    }

    __syncthreads();

    // ---------------- coalesced copy-out ----------------
    char* kvt = KV + (size_t)(bb*64 + ntile) * TILE_B;
    #pragma unroll
    for (int i = 0; i < 12; ++i) {
        const int off = (i*256 + t) * 16;
        *(uint4*)(kvt + off) = *(const uint4*)(lds + off);
    }
    char* qg = (char*)Qf + ((size_t)(bb*NN + nblk)) * NC2 * 2;
    #pragma unroll
    for (int i = 0; i < 4; ++i) {
        const int g = (i*256 + t) * 16;
        const int sidx = 49152 + (g ^ (((g >> 8) & 15) << 4));
        *(uint4*)(qg + g) = *(const uint4*)(lds + sidx);
    }
}

// ---------------------------------------------------------------------------
// Phase 2: flash attention, K direct from L2 (coalesced fragment-major
// planes), V-only LDS double-buffer, ONE plain __syncthreads per iter.
//   iter t: QK (global K loads + MFMA) -> softmax ->
//           __syncthreads (V(t) writes landed; V(t-1) readers all done) ->
//           issue V(t+1) into buf^1 -> pack/PV from buf.
// No manual vmcnt; compiler-managed waits only.
// ---------------------------------------------------------------------------
__global__ __launch_bounds__(256, 2) void attn_kernel(
    const unsigned short* __restrict__ Qf, const char* __restrict__ KV,
    const float* __restrict__ yg, const float* __restrict__ gamma,
    float* __restrict__ outp)
{
    __shared__ __align__(16) char vls[2][32768];

    const int bid = ((blockIdx.x & 7) << 6) + (blockIdx.x >> 3);
    const int bb = bid >> 5;
    const int m0 = (bid & 31) * 128;
    const int t    = threadIdx.x;
    const int lane = t & 63;
    const int wv   = t >> 6;
    const int qcol = lane & 31;
    const int s    = lane >> 5;

    f16x8 qf[8];
    {
        const char* qrow = (const char*)Qf +
            (((size_t)bb*NN + m0 + wv*32 + qcol) * NC2) * 2;
        #pragma unroll
        for (int ks = 0; ks < 8; ++ks)
            qf[ks] = *(const f16x8*)(qrow + ks*32 + s*16);
    }

    f32x16 acc[8];
    #pragma unroll
    for (int ob = 0; ob < 8; ++ob) acc[ob] = (f32x16)(0.0f);
    float m_run = -3.0e38f, l_run = 0.0f;

    const char* kvb = KV + (size_t)bb * 64 * TILE_B;

    // prologue: issue V(0) into vls[0]
    #pragma unroll
    for (int i = 0; i < 8; ++i)
        gload16(kvb + 16384 + ((i*256 + t) << 4), vls[0] + ((i*256 + wv*64) << 4));

    #pragma unroll 1
    for (int it = 0; it < 64; ++it) {
        const char* kglob = kvb + (size_t)it * TILE_B;

        // --- QK over all 64 keys; K fragments straight from L2 ---
        f32x16 sA = (f32x16)(0.0f), sB = (f32x16)(0.0f);
        {
            __builtin_amdgcn_s_setprio(1);
            #pragma unroll
            for (int ks = 0; ks < 8; ++ks) {
                const char* pl = kglob + ((ks*2 + s) << 10) + qcol*16;
                f16x8 kfA = *(const f16x8*)(pl);
                f16x8 kfB = *(const f16x8*)(pl + 512);
                sA = __builtin_amdgcn_mfma_f32_32x32x16_f16(kfA, qf[ks], sA, 0, 0, 0);
                sB = __builtin_amdgcn_mfma_f32_32x32x16_f16(kfB, qf[ks], sB, 0, 0, 0);
            }
            __builtin_amdgcn_s_setprio(0);
        }

        // --- JOINT online softmax (exp2 domain, tree reductions) ---
        float pa[16], pb[16];
        {
            float mx[16];
            #pragma unroll
            for (int r = 0; r < 16; ++r) mx[r] = fmaxf(sA[r], sB[r]);
            #pragma unroll
            for (int st = 8; st >= 1; st >>= 1)
                #pragma unroll
                for (int r = 0; r < st; ++r) mx[r] = fmaxf(mx[r], mx[r + st]);
            float pmax = fmaxf(mx[0], __shfl_xor(mx[0], 32));
            if (__any(pmax > m_run + 11.5415603f)) {   // T13 defer-max (8/ln2)
                const float mn = fmaxf(m_run, pmax);
                const float sc = __builtin_amdgcn_exp2f(m_run - mn);
                m_run = mn; l_run *= sc;
                #pragma unroll
                for (int ob = 0; ob < 8; ++ob)
                    #pragma unroll
                    for (int r = 0; r < 16; ++r) acc[ob][r] *= sc;
            }
            #pragma unroll
            for (int r = 0; r < 16; ++r) pa[r] = __builtin_amdgcn_exp2f(sA[r] - m_run);
            #pragma unroll
            for (int r = 0; r < 16; ++r) pb[r] = __builtin_amdgcn_exp2f(sB[r] - m_run);
            float sm[16];
            #pragma unroll
            for (int r = 0; r < 16; ++r) sm[r] = pa[r] + pb[r];
            #pragma unroll
            for (int st = 8; st >= 1; st >>= 1)
                #pragma unroll
                for (int r = 0; r < st; ++r) sm[r] += sm[r + st];
            l_run += sm[0] + __shfl_xor(sm[0], 32);
        }

        // --- single barrier: V(it) writes landed; V(it-1) readers done ---
        __syncthreads();

        // --- issue V(it+1) into the other buffer ---
        if (it < 63) {
            const char* nsrc = kvb + (size_t)(it + 1) * TILE_B + 16384;
            char* vdst = (char*)vls[(it + 1) & 1];
            #pragma unroll
            for (int i = 0; i < 8; ++i)
                gload16(nsrc + ((i*256 + t) << 4), vdst + ((i*256 + wv*64) << 4));
        }

        // --- 4 interleaved steps: pack(kb,ks2) then its 8 PV MFMAs ---
        const char* vbuf = vls[it & 1];
        #pragma unroll
        for (int st4 = 0; st4 < 4; ++st4) {
            const int kb  = st4 >> 1;
            const int ks2 = st4 & 1;
            const float* pp = kb ? pb : pa;
            const int b0 = ks2 * 8;
            unsigned int pA0 = pk2(pp[b0+0], pp[b0+1]);
            unsigned int pA1 = pk2(pp[b0+2], pp[b0+3]);
            unsigned int pB0 = pk2(pp[b0+4], pp[b0+5]);
            unsigned int pB1 = pk2(pp[b0+6], pp[b0+7]);
            const unsigned int lv0 = s ? pB0 : pA0;
            const unsigned int lv1 = s ? pB1 : pA1;
            const unsigned int sd0 = s ? pA0 : pB0;
            const unsigned int sd1 = s ? pA1 : pB1;
            const unsigned int rv0 = (unsigned int)__shfl_xor((int)sd0, 32);
            const unsigned int rv1 = (unsigned int)__shfl_xor((int)sd1, 32);
            union { unsigned int w[4]; f16x8 v; } u;
            u.w[0] = s ? rv0 : lv0;
            u.w[1] = s ? rv1 : lv1;
            u.w[2] = s ? lv0 : rv0;
            u.w[3] = s ? lv1 : rv1;
            const f16x8 pbx = u.v;
            const char* vplane = vbuf + (((kb<<2) + (ks2<<1) + s) << 12) + qcol*16;
            __builtin_amdgcn_s_setprio(1);
            #pragma unroll
            for (int ob = 0; ob < 8; ++ob) {
                f16x8 vf = *(const f16x8*)(vplane + ob*512);
                acc[ob] = __builtin_amdgcn_mfma_f32_32x32x16_f16(vf, pbx, acc[ob], 0, 0, 0);
            }
            __builtin_amdgcn_s_setprio(0);
        }
    }

    // --- epilogue: out[o][n] = gamma * acc/l + y ---
    const float ga   = gamma[0];
    const float invl = 1.0f / l_run;
    const int n = m0 + wv*32 + qcol;
    #pragma unroll
    for (int ob = 0; ob < 8; ++ob) {
        #pragma unroll
        for (int r = 0; r < 16; ++r) {
            const int o = ob*32 + (r&3) + 8*(r>>2) + 4*s;
            const size_t a = ((size_t)(bb*NC + o))*NN + n;
            outp[a] = fmaf(acc[ob][r]*invl, ga, yg[a]);
        }
    }
}

extern "C" void kernel_launch(void* const* d_in, const int* in_sizes, int n_in,
                              void* d_out, int out_size, void* d_ws, size_t ws_size,
                              hipStream_t stream) {
    (void)in_sizes; (void)n_in; (void)out_size; (void)ws_size;
    const float* x     = (const float*)d_in[0];
    const float* y     = (const float*)d_in[1];
    const float* Wq    = (const float*)d_in[2];
    const float* bq    = (const float*)d_in[3];
    const float* Wk    = (const float*)d_in[4];
    const float* bk    = (const float*)d_in[5];
    const float* Wv    = (const float*)d_in[6];
    const float* bv    = (const float*)d_in[7];
    const float* gamma = (const float*)d_in[8];
    float* out = (float*)d_out;

    unsigned short* Qf = (unsigned short*)d_ws;              // 16 MB f16
    char* KV = (char*)(Qf + (size_t)NB*NN*NC2);              // 48 MB tiles

    qkv_kernel<<<dim3(1024), dim3(256), 0, stream>>>(
        x, y, Wq, bq, Wk, bk, Wv, bv, Qf, KV);
    attn_kernel<<<dim3(512), dim3(256), 0, stream>>>(
        Qf, KV, y, gamma, out);
}

// Round 16
// 302.409 us; speedup vs baseline: 1.0981x; 1.0981x over previous
//
#include <hip/hip_runtime.h>
#include <stdint.h>

using f32x4  = __attribute__((ext_vector_type(4))) float;
using f32x16 = __attribute__((ext_vector_type(16))) float;
using f16x8  = __attribute__((ext_vector_type(8))) _Float16;

#define NB  16
#define NC  256
#define NC2 128
#define NN  4096
#define TILE_B 49152   // 48 KB/tile: K 16K (64n x 256B swz) + V 32K (8 planes x 256o x 16B)
#define LOG2E 1.44269504f

__device__ __forceinline__ unsigned int pk2(float a, float b) {
    auto h = __builtin_amdgcn_cvt_pkrtz(a, b);   // __fp16 ext_vector(2)
    return __builtin_bit_cast(unsigned int, h);
}

__device__ __forceinline__ f16x8 pack8(f32x4 a, f32x4 b) {
    union { unsigned int w[4]; f16x8 v; } u;
    u.w[0] = pk2(a[0], a[1]); u.w[1] = pk2(a[2], a[3]);
    u.w[2] = pk2(b[0], b[1]); u.w[3] = pk2(b[2], b[3]);
    return u.v;
}

__device__ __forceinline__ void gload16(const void* g, void* l) {
    __builtin_amdgcn_global_load_lds(
        (const __attribute__((address_space(1))) unsigned int*)g,
        (__attribute__((address_space(3))) unsigned int*)l, 16, 0, 0);
}

// ---------------------------------------------------------------------------
// Phase 1: 1x1-conv projections as MFMA f16 GEMM, LDS-staged epilogue.
// (EXACT round-13 version — proven across 5 rounds incl. post-timing.)
// Q pre-scaled by log2(e); K rows-n swizzled; V granule-transposed [g][o][16B].
// ---------------------------------------------------------------------------
__global__ __launch_bounds__(256, 2) void qkv_kernel(
    const float* __restrict__ x, const float* __restrict__ y,
    const float* __restrict__ Wq, const float* __restrict__ bq,
    const float* __restrict__ Wk, const float* __restrict__ bk,
    const float* __restrict__ Wv, const float* __restrict__ bv,
    unsigned short* __restrict__ Qf, char* __restrict__ KV)
{
    __shared__ __align__(16) char lds[65536];

    const int bid   = blockIdx.x;
    const int ntile = bid & 63;
    const int bb    = bid >> 6;
    const int nblk  = ntile * 64;

    const int t    = threadIdx.x;
    const int lane = t & 63;
    const int wid  = t >> 6;
    const int l31  = lane & 31;
    const int s    = lane >> 5;

    // ---------------- pass 1: Q (waves 0-1) / K (waves 2-3) ----------------
    {
        const bool isQ = (wid < 2);
        const float* srcb = (isQ ? x : y) + (size_t)bb * NC * NN;
        const float* W    = isQ ? Wq : Wk;
        const float* bias = isQ ? bq : bk;
        const int wo = (wid & 1) * 64;
        const int base = isQ ? 49152 : 0;
        const float osc = isQ ? LOG2E : 1.0f;

        f32x16 acc[2][2];
        #pragma unroll
        for (int a = 0; a < 2; ++a)
            #pragma unroll
            for (int bc = 0; bc < 2; ++bc) acc[a][bc] = (f32x16)(0.0f);

        #pragma unroll 4
        for (int ks = 0; ks < 16; ++ks) {
            const int c0 = ks * 16 + s * 8;
            f16x8 wf[2], xf[2];
            #pragma unroll
            for (int a = 0; a < 2; ++a) {
                const float* wr = W + (size_t)(wo + a * 32 + l31) * NC + c0;
                wf[a] = pack8(*(const f32x4*)wr, *(const f32x4*)(wr + 4));
            }
            #pragma unroll
            for (int bc = 0; bc < 2; ++bc) {
                const float* xc = srcb + (size_t)c0 * NN + nblk + bc * 32 + l31;
                f32x4 v0, v1;
                v0[0] = xc[0*NN]; v0[1] = xc[1*NN]; v0[2] = xc[2*NN]; v0[3] = xc[3*NN];
                v1[0] = xc[4*NN]; v1[1] = xc[5*NN]; v1[2] = xc[6*NN]; v1[3] = xc[7*NN];
                xf[bc] = pack8(v0, v1);
            }
            #pragma unroll
            for (int a = 0; a < 2; ++a)
                #pragma unroll
                for (int bc = 0; bc < 2; ++bc)
                    acc[a][bc] = __builtin_amdgcn_mfma_f32_32x32x16_f16(
                        wf[a], xf[bc], acc[a][bc], 0, 0, 0);
        }

        #pragma unroll
        for (int a = 0; a < 2; ++a) {
            #pragma unroll
            for (int bc = 0; bc < 2; ++bc) {
                const int nr = bc * 32 + l31;
                #pragma unroll
                for (int g = 0; g < 4; ++g) {
                    const int o0 = wo + a * 32 + 8 * g + 4 * s;
                    const f32x4 bv4 = *(const f32x4*)(bias + o0);
                    union { unsigned int w[2]; uint2 u2; } pk;
                    pk.w[0] = pk2((acc[a][bc][g*4+0] + bv4[0]) * osc,
                                  (acc[a][bc][g*4+1] + bv4[1]) * osc);
                    pk.w[1] = pk2((acc[a][bc][g*4+2] + bv4[2]) * osc,
                                  (acc[a][bc][g*4+3] + bv4[3]) * osc);
                    const int dst = base + nr*256 +
                        (((o0 >> 3) << 4) ^ ((nr & 15) << 4)) + (o0 & 7) * 2;
                    *(uint2*)(lds + dst) = pk.u2;
                }
            }
        }
    }

    // ---------------- pass 2: V (all waves, swapped mfma) ----------------
    {
        const float* srcb = y + (size_t)bb * NC * NN;
        const int wo = wid * 64;

        f32x16 acc[2][2];
        #pragma unroll
        for (int a = 0; a < 2; ++a)
            #pragma unroll
            for (int bc = 0; bc < 2; ++bc) acc[a][bc] = (f32x16)(0.0f);

        #pragma unroll 4
        for (int ks = 0; ks < 16; ++ks) {
            const int c0 = ks * 16 + s * 8;
            f16x8 wf[2], xf[2];
            #pragma unroll
            for (int a = 0; a < 2; ++a) {
                const float* wr = Wv + (size_t)(wo + a * 32 + l31) * NC + c0;
                wf[a] = pack8(*(const f32x4*)wr, *(const f32x4*)(wr + 4));
            }
            #pragma unroll
            for (int bc = 0; bc < 2; ++bc) {
                const float* xc = srcb + (size_t)c0 * NN + nblk + bc * 32 + l31;
                f32x4 v0, v1;
                v0[0] = xc[0*NN]; v0[1] = xc[1*NN]; v0[2] = xc[2*NN]; v0[3] = xc[3*NN];
                v1[0] = xc[4*NN]; v1[1] = xc[5*NN]; v1[2] = xc[6*NN]; v1[3] = xc[7*NN];
                xf[bc] = pack8(v0, v1);
            }
            #pragma unroll
            for (int a = 0; a < 2; ++a)
                #pragma unroll
                for (int bc = 0; bc < 2; ++bc)
                    acc[a][bc] = __builtin_amdgcn_mfma_f32_32x32x16_f16(
                        xf[bc], wf[a], acc[a][bc], 0, 0, 0);
        }

        #pragma unroll
        for (int a = 0; a < 2; ++a) {
            const int o = wo + a * 32 + l31;
            const float bvo = bv[o];
            #pragma unroll
            for (int bc = 0; bc < 2; ++bc) {
                #pragma unroll
                for (int g = 0; g < 4; ++g) {
                    const int nr = bc * 32 + 8 * g + 4 * s;   // keys nr..nr+3
                    union { unsigned int w[2]; uint2 u2; } pk;
                    pk.w[0] = pk2(acc[a][bc][g*4+0] + bvo, acc[a][bc][g*4+1] + bvo);
                    pk.w[1] = pk2(acc[a][bc][g*4+2] + bvo, acc[a][bc][g*4+3] + bvo);
                    const int dst = 16384 + ((nr >> 3) << 12) + o*16 + (nr & 7) * 2;
                    *(uint2*)(lds + dst) = pk.u2;
                }
            }
        }
    }

    __syncthreads();

    // ---------------- coalesced copy-out ----------------
    char* kvt = KV + (size_t)(bb*64 + ntile) * TILE_B;
    #pragma unroll
    for (int i = 0; i < 12; ++i) {
        const int off = (i*256 + t) * 16;
        *(uint4*)(kvt + off) = *(const uint4*)(lds + off);
    }
    char* qg = (char*)Qf + ((size_t)(bb*NN + nblk)) * NC2 * 2;
    #pragma unroll
    for (int i = 0; i < 4; ++i) {
        const int g = (i*256 + t) * 16;
        const int sidx = 49152 + (g ^ (((g >> 8) & 15) << 4));
        *(uint4*)(qg + g) = *(const uint4*)(lds + sidx);
    }
}

// ---------------------------------------------------------------------------
// Phase 2: flash attention — K single-buffer (16K) + V DOUBLE-buffer (2x32K)
// = 80 KB LDS (2 blocks/CU = exactly 160 KB). V(t+1) issued at the TOP of
// iter t (a full iteration of flight time); K(t+1) issued after the post-QK
// barrier (single K buffer safe: QK reads consumed before that barrier).
// Ledger: top queue [V(t)8, K(t)4]; issue V(t+1) -> 20 outstanding;
// vmcnt(8) retires exactly V(t)+K(t). 3 barriers/iter, all waits slack-rich.
// ---------------------------------------------------------------------------
__global__ __launch_bounds__(256, 2) void attn_kernel(
    const unsigned short* __restrict__ Qf, const char* __restrict__ KV,
    const float* __restrict__ yg, const float* __restrict__ gamma,
    float* __restrict__ outp)
{
    __shared__ __align__(16) char kls[16384];
    __shared__ __align__(16) char vls[2][32768];

    const int bid = ((blockIdx.x & 7) << 6) + (blockIdx.x >> 3);
    const int bb = bid >> 5;
    const int m0 = (bid & 31) * 128;
    const int t    = threadIdx.x;
    const int lane = t & 63;
    const int wv   = t >> 6;
    const int qcol = lane & 31;
    const int s    = lane >> 5;

    f16x8 qf[8];
    {
        const char* qrow = (const char*)Qf +
            (((size_t)bb*NN + m0 + wv*32 + qcol) * NC2) * 2;
        #pragma unroll
        for (int ks = 0; ks < 8; ++ks)
            qf[ks] = *(const f16x8*)(qrow + ks*32 + s*16);
    }

    f32x16 acc[8];
    #pragma unroll
    for (int ob = 0; ob < 8; ++ob) acc[ob] = (f32x16)(0.0f);
    float m_run = -3.0e38f, l_run = 0.0f;

    const char* kvb = KV + (size_t)bb * 64 * TILE_B;

    // prologue: issue V(0) [8] then K(0) [4]  (queue order [V,K] as steady state)
    #pragma unroll
    for (int i = 0; i < 8; ++i)
        gload16(kvb + 16384 + ((i*256 + t) << 4), vls[0] + ((i*256 + wv*64) << 4));
    #pragma unroll
    for (int i = 0; i < 4; ++i)
        gload16(kvb + ((i*256 + t) << 4), kls + ((i*256 + wv*64) << 4));

    #pragma unroll 1
    for (int it = 0; it < 64; ++it) {
        const char* nsrc = kvb + (size_t)((it + 1) & 63) * TILE_B;

        // --- issue V(it+1) into the other V buffer (released by the
        //     end-of-iter barrier of it-1) ---
        {
            char* vdst = (char*)vls[(it + 1) & 1];
            #pragma unroll
            for (int i = 0; i < 8; ++i)
                gload16(nsrc + 16384 + ((i*256 + t) << 4), vdst + ((i*256 + wv*64) << 4));
        }

        // --- V(it)+K(it) retired (V(it+1) 8 loads stay in flight) ---
        asm volatile("s_waitcnt vmcnt(8)" ::: "memory");
        __builtin_amdgcn_s_barrier();
        asm volatile("" ::: "memory");

        // --- QK over all 64 keys, interleaved sA/sB chains ---
        f32x16 sA = (f32x16)(0.0f), sB = (f32x16)(0.0f);
        {
            const int keyA = qcol, keyB = 32 + qcol;
            const int rbA = keyA * 256, rbB = keyB * 256;
            const int swA = (keyA & 15) << 4, swB = (keyB & 15) << 4;
            __builtin_amdgcn_s_setprio(1);
            #pragma unroll
            for (int ks = 0; ks < 8; ++ks) {
                f16x8 kfA = *(const f16x8*)(kls + rbA + ((ks*32 + s*16) ^ swA));
                f16x8 kfB = *(const f16x8*)(kls + rbB + ((ks*32 + s*16) ^ swB));
                sA = __builtin_amdgcn_mfma_f32_32x32x16_f16(kfA, qf[ks], sA, 0, 0, 0);
                sB = __builtin_amdgcn_mfma_f32_32x32x16_f16(kfB, qf[ks], sB, 0, 0, 0);
            }
            __builtin_amdgcn_s_setprio(0);
        }

        // --- all QK reads consumed; safe to overwrite kls ---
        asm volatile("" ::: "memory");
        __builtin_amdgcn_s_barrier();
        asm volatile("" ::: "memory");

        // --- issue K(it+1) into kls ---
        #pragma unroll
        for (int i = 0; i < 4; ++i)
            gload16(nsrc + ((i*256 + t) << 4), kls + ((i*256 + wv*64) << 4));

        // --- JOINT online softmax (exp2 domain, tree reductions) ---
        float pa[16], pb[16];
        {
            float mx[16];
            #pragma unroll
            for (int r = 0; r < 16; ++r) mx[r] = fmaxf(sA[r], sB[r]);
            #pragma unroll
            for (int st = 8; st >= 1; st >>= 1)
                #pragma unroll
                for (int r = 0; r < st; ++r) mx[r] = fmaxf(mx[r], mx[r + st]);
            float pmax = fmaxf(mx[0], __shfl_xor(mx[0], 32));
            if (__any(pmax > m_run + 11.5415603f)) {   // T13 defer-max (8/ln2)
                const float mn = fmaxf(m_run, pmax);
                const float sc = __builtin_amdgcn_exp2f(m_run - mn);
                m_run = mn; l_run *= sc;
                #pragma unroll
                for (int ob = 0; ob < 8; ++ob)
                    #pragma unroll
                    for (int r = 0; r < 16; ++r) acc[ob][r] *= sc;
            }
            #pragma unroll
            for (int r = 0; r < 16; ++r) pa[r] = __builtin_amdgcn_exp2f(sA[r] - m_run);
            #pragma unroll
            for (int r = 0; r < 16; ++r) pb[r] = __builtin_amdgcn_exp2f(sB[r] - m_run);
            float sm[16];
            #pragma unroll
            for (int r = 0; r < 16; ++r) sm[r] = pa[r] + pb[r];
            #pragma unroll
            for (int st = 8; st >= 1; st >>= 1)
                #pragma unroll
                for (int r = 0; r < st; ++r) sm[r] += sm[r + st];
            l_run += sm[0] + __shfl_xor(sm[0], 32);
        }

        // --- 4 interleaved steps: pack(kb,ks2) then its 8 PV MFMAs ---
        const char* vbuf = vls[it & 1];
        #pragma unroll
        for (int st4 = 0; st4 < 4; ++st4) {
            const int kb  = st4 >> 1;
            const int ks2 = st4 & 1;
            const float* pp = kb ? pb : pa;
            const int b0 = ks2 * 8;
            unsigned int pA0 = pk2(pp[b0+0], pp[b0+1]);
            unsigned int pA1 = pk2(pp[b0+2], pp[b0+3]);
            unsigned int pB0 = pk2(pp[b0+4], pp[b0+5]);
            unsigned int pB1 = pk2(pp[b0+6], pp[b0+7]);
            const unsigned int lv0 = s ? pB0 : pA0;
            const unsigned int lv1 = s ? pB1 : pA1;
            const unsigned int sd0 = s ? pA0 : pB0;
            const unsigned int sd1 = s ? pA1 : pB1;
            const unsigned int rv0 = (unsigned int)__shfl_xor((int)sd0, 32);
            const unsigned int rv1 = (unsigned int)__shfl_xor((int)sd1, 32);
            union { unsigned int w[4]; f16x8 v; } u;
            u.w[0] = s ? rv0 : lv0;
            u.w[1] = s ? rv1 : lv1;
            u.w[2] = s ? lv0 : rv0;
            u.w[3] = s ? lv1 : rv1;
            const f16x8 pbx = u.v;
            const char* vplane = vbuf + (((kb<<2) + (ks2<<1) + s) << 12) + qcol*16;
            __builtin_amdgcn_s_setprio(1);
            #pragma unroll
            for (int ob = 0; ob < 8; ++ob) {
                f16x8 vf = *(const f16x8*)(vplane + ob*512);
                acc[ob] = __builtin_amdgcn_mfma_f32_32x32x16_f16(vf, pbx, acc[ob], 0, 0, 0);
            }
            __builtin_amdgcn_s_setprio(0);
        }

        // --- end-of-iter: PV reads of vls[it&1] done -> releasable next iter ---
        asm volatile("" ::: "memory");
        __builtin_amdgcn_s_barrier();
        asm volatile("" ::: "memory");
    }
    asm volatile("s_waitcnt vmcnt(0)" ::: "memory");

    // --- epilogue: out[o][n] = gamma * acc/l + y ---
    const float ga   = gamma[0];
    const float invl = 1.0f / l_run;
    const int n = m0 + wv*32 + qcol;
    #pragma unroll
    for (int ob = 0; ob < 8; ++ob) {
        #pragma unroll
        for (int r = 0; r < 16; ++r) {
            const int o = ob*32 + (r&3) + 8*(r>>2) + 4*s;
            const size_t a = ((size_t)(bb*NC + o))*NN + n;
            outp[a] = fmaf(acc[ob][r]*invl, ga, yg[a]);
        }
    }
}

extern "C" void kernel_launch(void* const* d_in, const int* in_sizes, int n_in,
                              void* d_out, int out_size, void* d_ws, size_t ws_size,
                              hipStream_t stream) {
    (void)in_sizes; (void)n_in; (void)out_size; (void)ws_size;
    const float* x     = (const float*)d_in[0];
    const float* y     = (const float*)d_in[1];
    const float* Wq    = (const float*)d_in[2];
    const float* bq    = (const float*)d_in[3];
    const float* Wk    = (const float*)d_in[4];
    const float* bk    = (const float*)d_in[5];
    const float* Wv    = (const float*)d_in[6];
    const float* bv    = (const float*)d_in[7];
    const float* gamma = (const float*)d_in[8];
    float* out = (float*)d_out;

    unsigned short* Qf = (unsigned short*)d_ws;              // 16 MB f16
    char* KV = (char*)(Qf + (size_t)NB*NN*NC2);              // 48 MB tiles

    qkv_kernel<<<dim3(1024), dim3(256), 0, stream>>>(
        x, y, Wq, bq, Wk, bk, Wv, bv, Qf, KV);
    attn_kernel<<<dim3(512), dim3(256), 0, stream>>>(
        Qf, KV, y, gamma, out);
}